// Round 7
// baseline (143.383 us; speedup 1.0000x reference)
//
#include <hip/hip_runtime.h>

// ISTA T=5, LAM=0.1, B=L=4096, K=128.
// R10: bf16 LDS ring + one-shot convert + persistent sliding windows.
//  u = corr(y - corr(y,h), rev(h)) == (interior) one 255-tap correlation
//    G[t] = [t in [-63,64]] h[64-t] - ac[|t-1|],  ac[tau]=sum_m h[m]h[m+tau].
//  Stream blocks (16 rows x 1024 cols, 4 phases of 256 cols):
//    phase k: BARRIER; cvt+ds_write seg k+2 (regs loaded phase k-1);
//             issue global loads seg k+3 -> regs; compute step k from ring
//             segs k-1..k+1 (bf16, 1 ds_read_b128 per window, cvt-free).
//  Slots {k-1,k,k+1,k+2} mod 4 are distinct -> race-free with one barrier
//  per phase; HBM latency of seg k+3 hides under compute k (T14 split).
//  B-windows slide with stride 64 ACROSS phases: 2 new frags per tile.
//  r-truncation affects cols [0,64) u [L-64,L): exact two-pass edge blocks
//  (same launch, disjoint columns) fix those strips.
//  ISTA closed form (constant u): x_5 = 5*soft(s*u, LAM).

typedef __bf16 bf16;
typedef __bf16 bf16x4 __attribute__((ext_vector_type(4)));
typedef __bf16 bf16x8 __attribute__((ext_vector_type(8)));
typedef float f32x4 __attribute__((ext_vector_type(4)));

#define LAM 0.1f
#define RP 1032                 // ring row pitch in bf16 (1024 + 8 pad)
#define LDSB (16 * RP * 2)      // 33024 B -> 4 blocks/CU
// ws layout in bf16 elems (16-B aligned fragments):
#define WS_AG 0        // AG frag:  lane*128 + dd*8, dd<9
#define WS_ZERO 80     // (kept from R8/R9; unused by R10 stream path)
#define WS_A1 8192     // A1e frag: lane*64  + dd*8, dd<5
#define WS_A2 12288    // A2e frag: lane*64  + dd*8, dd<5
// edge-path LDS partition:
#define PYE 360        // y strip pitch (352 needed)
#define PRE 216        // r strip pitch (208 needed)

// ---------------- prep: G + lane-layout A-fragment tables ----------------
__global__ __launch_bounds__(256) void ista_prep(const float* __restrict__ h,
                                                 bf16* __restrict__ ws) {
  __shared__ float hs[256];    // h zero-padded
  __shared__ float acp[256];   // autocorr partials
  __shared__ bf16 gp[384];     // G[t] at p=t+144, zero outside
  const int tid = threadIdx.x;
  hs[tid] = (tid < 128) ? h[tid] : 0.f;
  gp[tid] = (bf16)0.f;
  if (tid < 128) gp[256 + tid] = (bf16)0.f;
  __syncthreads();
  const int tau = tid & 127;
  {  // split ac over two halves x 4 accumulators (short dep chains)
    const int m0 = (tid >> 7) * 64;
    float p0 = 0.f, p1 = 0.f, p2 = 0.f, p3 = 0.f;
    for (int m = m0; m < m0 + 64; m += 4) {
      p0 += hs[m] * hs[m + tau];     p1 += hs[m + 1] * hs[m + 1 + tau];
      p2 += hs[m + 2] * hs[m + 2 + tau]; p3 += hs[m + 3] * hs[m + 3 + tau];
    }
    acp[tid] = (p0 + p1) + (p2 + p3);
  }
  __syncthreads();
  if (tid < 128) {
    float ac = acp[tid] + acp[tid + 128];
    float g1 = (tau <= 63) ? hs[63 - tau] : 0.f;
    gp[145 + tau] = (bf16)(g1 - ac);
    if (tau > 0) {
      float g2 = (tau <= 64) ? hs[63 + tau] : 0.f;
      gp[145 - tau] = (bf16)(g2 - ac);
    }
  }
  __syncthreads();
  // AG lane-layout: A[m=li][k=quad*8+j] = G[144 + quad*8 - li + (dd-4)*32 + j]
  for (int i = tid; i < 1024; i += 256) {
    const int l = i >> 4, dd = i & 15;
    if (dd < 9) {
      const int o = 144 + (l >> 4) * 8 - (l & 15) + (dd - 4) * 32;
      bf16x8 a;
#pragma unroll
      for (int j = 0; j < 8; ++j) a[j] = gp[o + j];
      *reinterpret_cast<bf16x8*>(ws + WS_AG + l * 128 + dd * 8) = a;
    }
  }
  if (tid < 8) ws[WS_ZERO + tid] = (bf16)0.f;
  // edge Toeplitz tables: h1p[p]=h[p-64], h2p[p]=-h[191-p] (zero outside)
  for (int i = tid; i < 512; i += 256) {
    const int l = i >> 3, dd = i & 7;
    if (dd < 5) {
      const int o = 127 + (l >> 4) * 8 - (l & 15) + (dd - 2) * 32;
      bf16x8 a1, a2;
#pragma unroll
      for (int j = 0; j < 8; ++j) {
        int p = o + j;
        int i1 = p - 64;
        a1[j] = ((unsigned)i1 < 128u) ? (bf16)hs[i1] : (bf16)0.f;
        int i2 = 191 - p;
        a2[j] = ((unsigned)i2 < 128u) ? (bf16)(-hs[i2]) : (bf16)0.f;
      }
      *reinterpret_cast<bf16x8*>(ws + WS_A1 + l * 64 + dd * 8) = a1;
      *reinterpret_cast<bf16x8*>(ws + WS_A2 + l * 64 + dd * 8) = a2;
    }
  }
}

// ---------------- fused: bf16-ring stream + edge two-pass -----------------
__global__ __launch_bounds__(256, 4) void ista_fused(
    const float* __restrict__ y, const bf16* __restrict__ ws,
    const float* __restrict__ step, float* __restrict__ out) {
  __shared__ __align__(16) char smem[LDSB];
  const int tid = threadIdx.x;
  const int lane = tid & 63;
  const int li = lane & 15;
  const int quad = lane >> 4;
  const int wave = tid >> 6;
  const int bid = blockIdx.x;
  const float s = step[0];

  if (bid < 1024) {
    // -------- stream: 16 rows x 1024 cols, 4 phases of 256 cols -----------
    // rowgroup-major: all col-blocks of a rowgroup share an XCD (bid%8 const).
    const int b0 = (bid & 255) * 16;
    const int cb = (bid >> 8) * 1024;
    bf16* ring = reinterpret_cast<bf16*>(smem);

    bf16x8 AG[9];
#pragma unroll
    for (int dd = 0; dd < 9; ++dd)
      AG[dd] = *reinterpret_cast<const bf16x8*>(ws + WS_AG + lane * 128 + dd * 8);

    // staging partition: thread = (row sr, 16-col group c16)
    const int sr = tid >> 4;
    const int c16 = tid & 15;
    const float* yrow = y + (size_t)(b0 + sr) * 4096;
    bf16* wdst = ring + sr * RP;
    float st[16];

#define LOAD16(m)                                                         \
  {                                                                       \
    _Pragma("unroll") for (int u = 0; u < 4; ++u) {                       \
      int gcol = cb + 256 * (m) + 16 * c16 + 4 * u;                       \
      float4 v = {0.f, 0.f, 0.f, 0.f};                                    \
      if ((unsigned)gcol < 4096u)                                         \
        v = *reinterpret_cast<const float4*>(yrow + gcol);                \
      st[4 * u + 0] = v.x; st[4 * u + 1] = v.y;                           \
      st[4 * u + 2] = v.z; st[4 * u + 3] = v.w;                           \
    }                                                                     \
  }
#define CVTWRITE(m)                                                       \
  {                                                                       \
    bf16x8 lo, hi;                                                        \
    _Pragma("unroll") for (int j = 0; j < 8; ++j) {                       \
      lo[j] = (bf16)st[j]; hi[j] = (bf16)st[8 + j];                       \
    }                                                                     \
    int rc = (256 * (m) + 16 * c16 + 1024) & 1023;                        \
    *reinterpret_cast<bf16x8*>(wdst + rc) = lo;                           \
    *reinterpret_cast<bf16x8*>(wdst + rc + 8) = hi;                       \
  }

    // prologue: fill segs -1,0,1; leave seg 2 in regs for phase 0
    LOAD16(-1); CVTWRITE(-1);
    LOAD16(0);  CVTWRITE(0);
    LOAD16(1);  CVTWRITE(1);
    LOAD16(2);

    const int qo = quad << 3;
    const bf16* rowp = ring + li * RP;
    float* orow = out + (size_t)(b0 + li) * 4096 + cb + (quad << 2);
    bf16x8 B[9];

#define RFRAG(col) \
  (*reinterpret_cast<const bf16x8*>(rowp + (((col) + 1024) & 1023)))

#pragma unroll
    for (int k = 0; k < 4; ++k) {
      __syncthreads();               // seg k+1 visible; slot k+2 free
      if (k <= 2) CVTWRITE(k + 2);   // regs from phase k-1 (drained at barrier)
      if (k <= 1) LOAD16(k + 3);     // lands under compute k (+ barrier k+1)
      if (k == 0) {
#pragma unroll
        for (int dd = 0; dd < 9; ++dd)
          B[dd] = RFRAG(16 * wave + (dd - 4) * 32 + qo);
      }
#pragma unroll
      for (int j = 0; j < 4; ++j) {  // tiles tc = 256k + 16*wave + 64j
        const int tc = 256 * k + 16 * wave + 64 * j;
        f32x4 acc0 = {0.f, 0.f, 0.f, 0.f};
        f32x4 acc1 = {0.f, 0.f, 0.f, 0.f};
        acc0 = __builtin_amdgcn_mfma_f32_16x16x32_bf16(AG[0], B[0], acc0, 0, 0, 0);
        acc1 = __builtin_amdgcn_mfma_f32_16x16x32_bf16(AG[1], B[1], acc1, 0, 0, 0);
        acc0 = __builtin_amdgcn_mfma_f32_16x16x32_bf16(AG[2], B[2], acc0, 0, 0, 0);
        acc1 = __builtin_amdgcn_mfma_f32_16x16x32_bf16(AG[3], B[3], acc1, 0, 0, 0);
        acc0 = __builtin_amdgcn_mfma_f32_16x16x32_bf16(AG[4], B[4], acc0, 0, 0, 0);
        acc1 = __builtin_amdgcn_mfma_f32_16x16x32_bf16(AG[5], B[5], acc1, 0, 0, 0);
        acc0 = __builtin_amdgcn_mfma_f32_16x16x32_bf16(AG[6], B[6], acc0, 0, 0, 0);
        acc1 = __builtin_amdgcn_mfma_f32_16x16x32_bf16(AG[7], B[7], acc1, 0, 0, 0);
        acc0 = __builtin_amdgcn_mfma_f32_16x16x32_bf16(AG[8], B[8], acc0, 0, 0, 0);
        const int tabs = cb + tc;
        if (tabs >= 64 && tabs < 4032) {   // edge strips owned by edge blocks
          float4 xv;
#pragma unroll
          for (int e = 0; e < 4; ++e) {
            float su = s * (acc0[e] + acc1[e]);
            float ax = fabsf(su) - LAM;
            ax = ax > 0.f ? ax : 0.f;
            (&xv.x)[e] = 5.f * copysignf(ax, su);
          }
          *reinterpret_cast<float4*>(orow + tc) = xv;
        }
        if (k < 3 || j < 3) {        // slide to next tile (stride 64, global)
          B[0] = B[2]; B[1] = B[3]; B[2] = B[4]; B[3] = B[5]; B[4] = B[6];
          B[5] = B[7]; B[6] = B[8];
          B[7] = RFRAG(tc + 160 + qo);
          B[8] = RFRAG(tc + 192 + qo);
        }
      }
    }
#undef RFRAG
#undef CVTWRITE
#undef LOAD16
  } else {
    // ---------------- edge: exact two-pass on 64-col strips ----------------
    const int eid = bid - 1024;
    const int chunk0 = (eid & 1) ? (4096 - 64) : 0;
    const int b0 = (eid >> 1) * 16;
    bf16* ys = reinterpret_cast<bf16*>(smem);      // 16 x PYE, [-128, 224)
    bf16* rs = ys + 16 * PYE;                      // 16 x PRE, -r at [-64, 144)

    bf16x8 A1[5], A2[5];
#pragma unroll
    for (int dd = 0; dd < 5; ++dd) {
      A1[dd] = *reinterpret_cast<const bf16x8*>(ws + WS_A1 + lane * 64 + dd * 8);
      A2[dd] = *reinterpret_cast<const bf16x8*>(ws + WS_A2 + lane * 64 + dd * 8);
    }

    {  // stage y: 352 elems = 88 float4 per row (guarded)
      const int rr = tid >> 4;
      const int t = tid & 15;
      const float* yrow = y + (size_t)(b0 + rr) * 4096;
      bf16* dst = ys + rr * PYE;
#pragma unroll
      for (int k = 0; k < 6; ++k) {
        int s4 = t + 16 * k;
        if (s4 < 88) {
          int l = chunk0 - 128 + s4 * 4;
          float4 v;
          if (l >= 0 && l <= 4096 - 4) {
            v = *reinterpret_cast<const float4*>(yrow + l);
          } else {
            v.x = ((unsigned)(l + 0) < 4096u) ? yrow[l + 0] : 0.f;
            v.y = ((unsigned)(l + 1) < 4096u) ? yrow[l + 1] : 0.f;
            v.z = ((unsigned)(l + 2) < 4096u) ? yrow[l + 2] : 0.f;
            v.w = ((unsigned)(l + 3) < 4096u) ? yrow[l + 3] : 0.f;
          }
          bf16x4 bv;
          bv[0] = (bf16)v.x; bv[1] = (bf16)v.y; bv[2] = (bf16)v.z; bv[3] = (bf16)v.w;
          *reinterpret_cast<bf16x4*>(dst + s4 * 4) = bv;
        }
      }
    }
    __syncthreads();

    // conv1: tiles i0 = -64+16t, t in [0,13); emit -r (truncated to [0,L))
    for (int t = wave; t < 13; t += 4) {
      const int i0 = -64 + 16 * t;
      f32x4 acc;
      {
        bf16x4 yv = *reinterpret_cast<const bf16x4*>(
            ys + li * PYE + (i0 + 128) + quad * 4);
        acc[0] = -(float)yv[0]; acc[1] = -(float)yv[1];
        acc[2] = -(float)yv[2]; acc[3] = -(float)yv[3];
      }
#pragma unroll
      for (int dd = 0; dd < 5; ++dd) {
        bf16x8 b = *reinterpret_cast<const bf16x8*>(
            ys + li * PYE + (i0 + (dd - 2) * 32 + 128) + quad * 8);
        acc = __builtin_amdgcn_mfma_f32_16x16x32_bf16(A1[dd], b, acc, 0, 0, 0);
      }
      bf16x4 rv;
#pragma unroll
      for (int e = 0; e < 4; ++e) {
        int g = chunk0 + i0 + quad * 4 + e;
        float v = ((unsigned)g < 4096u) ? acc[e] : 0.f;
        rv[e] = (bf16)v;
      }
      *reinterpret_cast<bf16x4*>(rs + li * PRE + (i0 + 64) + quad * 4) = rv;
    }
    __syncthreads();

    // conv2 + closed-form epilogue: 4 tiles, one per wave
    {
      const int i0 = 16 * wave;
      f32x4 acc = {0.f, 0.f, 0.f, 0.f};
#pragma unroll
      for (int dd = 0; dd < 5; ++dd) {
        bf16x8 b = *reinterpret_cast<const bf16x8*>(
            rs + li * PRE + (i0 + (dd - 2) * 32 + 64) + quad * 8);
        acc = __builtin_amdgcn_mfma_f32_16x16x32_bf16(A2[dd], b, acc, 0, 0, 0);
      }
      float4 xv;
#pragma unroll
      for (int e = 0; e < 4; ++e) {
        float su = s * acc[e];
        float ax = fabsf(su) - LAM;
        ax = ax > 0.f ? ax : 0.f;
        (&xv.x)[e] = 5.f * copysignf(ax, su);
      }
      *reinterpret_cast<float4*>(
          out + (size_t)(b0 + li) * 4096 + chunk0 + i0 + quad * 4) = xv;
    }
  }
}

extern "C" void kernel_launch(void* const* d_in, const int* in_sizes, int n_in,
                              void* d_out, int out_size, void* d_ws,
                              size_t ws_size, hipStream_t stream) {
  const float* y = (const float*)d_in[0];
  const float* h = (const float*)d_in[1];
  const float* s = (const float*)d_in[2];
  float* out = (float*)d_out;
  bf16* ws = (bf16*)d_ws;   // 32 KB used
  ista_prep<<<dim3(1), dim3(256), 0, stream>>>(h, ws);
  // 1024 stream blocks (16 rows x 1024 cols, cols [64,4032)) + 512 edge
  // blocks (cols [0,64) and [4032,4096)) — disjoint outputs, one launch.
  ista_fused<<<dim3(1024 + 512), dim3(256), 0, stream>>>(y, ws, s, out);
}